// Round 7
// baseline (213.186 us; speedup 1.0000x reference)
//
#include <hip/hip_runtime.h>
#include <hip/hip_cooperative_groups.h>
#include <stdint.h>

namespace cg = cooperative_groups;

// x (16,256,64,64) fp32; 32 groups; 8 heads; head dim 32. All I/O fp32.
// Intermediates bf16. Softmax folded: att = diag(1/l) * sum_n exp(k) v.
// R7: att-output folds into w_proj: W2_b = wp @ blockdiag(att/l).
// R9: Q never materialized: out = (W2_b @ Wq_q) @ xn  (W3 = W2@Wq_q per batch).
// R10: kv_att single-pass 128x128 (64 K + 64 V rows); launches merged.
// R12: cooperative single-kernel path GATED on verified co-residency
//      (R6 post-mortem: 1024-block coop launch silently rejected -> zeros; the
//      runtime's occupancy model decides, not our 160KiB-pool arithmetic).
//      occ >= 4 blocks/CU -> coop (phases separated by grid.sync, all
//      grid-stride); else -> the R5 6-kernel pipeline verbatim (proven 208us).
#define BATCH 16
#define CCH   256
#define NSP   4096

typedef unsigned short u16;
typedef short  short8 __attribute__((ext_vector_type(8)));   // 8 bf16 (4 VGPRs)
typedef float  f32x4  __attribute__((ext_vector_type(4)));

__device__ __forceinline__ float bf2f(u16 h) {
  union { unsigned int u; float f; } x; x.u = ((unsigned int)h) << 16; return x.f;
}
__device__ __forceinline__ u16 f2bf(float f) {
  union { float f; unsigned int u; } x; x.f = f;
  unsigned int r = 0x7fffu + ((x.u >> 16) & 1u);
  return (u16)((x.u + r) >> 16);
}

#define GLB(p) ((__attribute__((address_space(1))) void*)(p))
#define LDSP(p) ((__attribute__((address_space(3))) void*)(p))

// ------------------------------------------------ phase A body: GN stats +
// att4 zero + weights fp32->bf16 + wqT transpose.
__device__ __forceinline__ void prep_body(int blk, int tid, const float* x,
                                          const float* wq, const float* wp,
                                          float2* stats, float* att4,
                                          u16* wbf, u16* wqT, u16* smem) {
  if (blk < 512) {
    float* red = (float*)(smem + 4608);         // bytes 9216.. (past ls region)
    {
      float* az = att4 + (size_t)blk * 264;     // zero 128*1056 over 512 blocks
      for (int i = tid; i < 264; i += 256) az[i] = 0.f;
    }
    const float4* xv = (const float4*)(x + (size_t)blk * 32768);
    float s = 0.f, ss = 0.f;
    for (int i = tid; i < 8192; i += 256) {
      float4 u = xv[i];
      s  += u.x + u.y + u.z + u.w;
      ss += u.x * u.x + u.y * u.y + u.z * u.z + u.w * u.w;
    }
#pragma unroll
    for (int off = 32; off > 0; off >>= 1) {
      s  += __shfl_down(s, off);
      ss += __shfl_down(ss, off);
    }
    const int wave = tid >> 6, lane = tid & 63;
    if (lane == 0) { red[wave * 2] = s; red[wave * 2 + 1] = ss; }
    __syncthreads();
    if (tid == 0) {
      const float S  = red[0] + red[2] + red[4] + red[6];
      const float SS = red[1] + red[3] + red[5] + red[7];
      const float mean = S * (1.f / 32768.f);
      const float var  = SS * (1.f / 32768.f) - mean * mean;
      stats[blk] = make_float2(mean, rsqrtf(var + 1e-5f));
    }
  } else if (blk < 768) {
    const int i = ((blk - 512) * 256 + tid) * 4;
    float4 v = (i < 196608) ? *(const float4*)(wq + i)
                            : *(const float4*)(wp + (i - 196608));
    ushort4 o;
    o.x = f2bf(v.x); o.y = f2bf(v.y); o.z = f2bf(v.z); o.w = f2bf(v.w);
    *(ushort4*)(wbf + i) = o;
  } else {
    u16 (*ls)[72] = (u16(*)[72])smem;
    const int t2 = blk - 768;
    const int c0 = (t2 & 3) * 64, r0 = (t2 >> 2) * 64;
#pragma unroll
    for (int j = 0; j < 4; ++j) {
      const int row = j * 16 + (tid >> 4), col = (tid & 15) * 4;
      float4 u = *(const float4*)(wq + (r0 + row) * 256 + c0 + col);
      ls[row][col]     = f2bf(u.x);
      ls[row][col + 1] = f2bf(u.y);
      ls[row][col + 2] = f2bf(u.z);
      ls[row][col + 3] = f2bf(u.w);
    }
    __syncthreads();
#pragma unroll
    for (int j = 0; j < 2; ++j) {
      const int crow = j * 32 + (tid >> 3), d8 = (tid & 7) * 8;
      u16 tmp[8];
#pragma unroll
      for (int k = 0; k < 8; ++k) tmp[k] = ls[d8 + k][crow];
      *(uint4*)(wqT + (c0 + crow) * 256 + r0 + d8) = *(uint4*)tmp;
    }
  }
}

// ------------------------------------------------ phase B body: GN apply + T
__device__ __forceinline__ void gn_apply_body(int n0t, int c0t, int b, int tid,
                                              const float* x, const float* gw,
                                              const float* gb, const float2* stats,
                                              u16* xnT, u16* smem) {
  u16 (*ls)[72] = (u16(*)[72])smem;             // [c][n], pad 72
  const int c0 = c0t * 64, n0 = n0t * 64;
#pragma unroll
  for (int r = 0; r < 4; ++r) {
    const int cc = (tid >> 4) + r * 16;
    const int nn = (tid & 15) * 4;
    const int c = c0 + cc;
    const float2 st = stats[b * 32 + (c >> 3)];
    const float wv = gw[c] * st.y;
    const float bv = gb[c] - st.x * wv;
    float4 u = *(const float4*)(x + ((size_t)b * CCH + c) * NSP + n0 + nn);
    ushort4 o;
    o.x = f2bf(u.x * wv + bv);
    o.y = f2bf(u.y * wv + bv);
    o.z = f2bf(u.z * wv + bv);
    o.w = f2bf(u.w * wv + bv);
    *(ushort4*)&ls[cc][nn] = o;
  }
  __syncthreads();
#pragma unroll
  for (int p = 0; p < 2; ++p) {
    const int idx = tid + p * 256;              // 0..511
    const int nn = idx >> 3;
    const int cb = (idx & 7) * 8;
    u16 tmp[8];
#pragma unroll
    for (int j = 0; j < 8; ++j) tmp[j] = ls[cb + j][nn];
    *(uint4*)(xnT + ((size_t)b * NSP + n0 + nn) * CCH + c0 + cb) = *(uint4*)tmp;
  }
}

// ------------------------------------------------ MFMA GEMM body, BK=64
// C[b][m][n] = sum_c A[m][c]*Bt[b][n][c]; A bf16 MxK(K=256), Bt bf16 NxK.
template <int OUTF32>
__device__ __forceinline__ void gemm_body(const u16* A, const u16* Bt,
                                          const float* bias, void* Cm, int M,
                                          int aBatch, long btStride, int ldc,
                                          int n0, int m0, int bz,
                                          int tid, u16* smem) {
  const int wave = tid >> 6, lane = tid & 63;
  const u16* Ab = A + (size_t)bz * aBatch;
  const u16* Bb = Bt + (size_t)bz * btStride;

  const int lrow = lane >> 3;                   // 0..7: row within 8-row group
  const int kcl  = ((lane & 7) ^ lrow) * 8;     // swizzled k element offset
  const u16* pA[4]; const u16* pB[4];
#pragma unroll
  for (int j = 0; j < 4; ++j) {
    const int row = j * 32 + wave * 8 + lrow;
    pA[j] = Ab + (size_t)(m0 + row) * CCH + kcl;
    pB[j] = Bb + (size_t)(n0 + row) * CCH + kcl;
  }
  u16* lA = smem;                               // 16 KB
  u16* lB = smem + 8192;                        // 16 KB

  const int wm = wave >> 1, wn = wave & 1;
  f32x4 acc[4][4];
#pragma unroll
  for (int i = 0; i < 4; ++i)
#pragma unroll
    for (int j = 0; j < 4; ++j) acc[i][j] = (f32x4){0.f, 0.f, 0.f, 0.f};

  for (int it = 0; it < 4; ++it) {              // K = 256, BK = 64
#pragma unroll
    for (int j = 0; j < 4; ++j) {
      __builtin_amdgcn_global_load_lds(GLB(pA[j]), LDSP(lA + (j * 256 + wave * 64) * 8), 16, 0, 0);
      __builtin_amdgcn_global_load_lds(GLB(pB[j]), LDSP(lB + (j * 256 + wave * 64) * 8), 16, 0, 0);
      pA[j] += 64; pB[j] += 64;
    }
    __syncthreads();
#pragma unroll
    for (int w = 0; w < 2; ++w) {               // two 32-k windows
      const int kcf = w * 4 + (lane >> 4);
      short8 af[4], bfr[4];
#pragma unroll
      for (int mt = 0; mt < 4; ++mt) {
        const int row = wm * 64 + mt * 16 + (lane & 15);
        af[mt] = *(const short8*)&lA[(row * 8 + (kcf ^ (row & 7))) * 8];
      }
#pragma unroll
      for (int nt = 0; nt < 4; ++nt) {
        const int row = wn * 64 + nt * 16 + (lane & 15);
        bfr[nt] = *(const short8*)&lB[(row * 8 + (kcf ^ (row & 7))) * 8];
      }
#pragma unroll
      for (int mt = 0; mt < 4; ++mt)
#pragma unroll
        for (int nt = 0; nt < 4; ++nt)
          acc[mt][nt] = __builtin_amdgcn_mfma_f32_16x16x32_bf16(af[mt], bfr[nt], acc[mt][nt], 0, 0, 0);
    }
    __syncthreads();
  }

  // epilogue: C/D frag col=lane&15, row=(lane>>4)*4+reg
  if (!OUTF32) {
    u16* cl = smem;                             // [128][136] u16 (34816 B)
#pragma unroll
    for (int mt = 0; mt < 4; ++mt)
#pragma unroll
      for (int nt = 0; nt < 4; ++nt)
#pragma unroll
        for (int r = 0; r < 4; ++r) {
          const int row = wm * 64 + mt * 16 + (lane >> 4) * 4 + r;
          const int col = wn * 64 + nt * 16 + (lane & 15);
          cl[row * 136 + col] = f2bf(acc[mt][nt][r]);
        }
    __syncthreads();
    u16* C = (u16*)Cm + (size_t)bz * (size_t)M * ldc;
#pragma unroll
    for (int j = 0; j < 8; ++j) {
      const int idx = tid + j * 256;            // 0..2047
      const int row = idx >> 4, chunk = idx & 15;
      *(uint4*)(C + (size_t)(m0 + row) * ldc + n0 + chunk * 8) =
          *(const uint4*)&cl[row * 136 + chunk * 8];
    }
  } else {
    float* clf = (float*)smem;                  // [64][132] fp32 per pass (33792 B)
    float* C = (float*)Cm + (size_t)bz * (size_t)M * ldc;
#pragma unroll
    for (int pass = 0; pass < 2; ++pass) {
      if (wm == pass) {
#pragma unroll
        for (int mt = 0; mt < 4; ++mt)
#pragma unroll
          for (int nt = 0; nt < 4; ++nt)
#pragma unroll
            for (int r = 0; r < 4; ++r) {
              const int rl = mt * 16 + (lane >> 4) * 4 + r;   // 0..63
              const int col = wn * 64 + nt * 16 + (lane & 15);
              clf[rl * 132 + col] = acc[mt][nt][r] + bias[m0 + pass * 64 + rl];
            }
      }
      __syncthreads();
#pragma unroll
      for (int j = 0; j < 8; ++j) {
        const int idx = tid + j * 256;          // 0..2047
        const int row = idx >> 5, chunk = idx & 31;
        *(float4*)(C + (size_t)(m0 + pass * 64 + row) * ldc + n0 + chunk * 4) =
            *(const float4*)&clf[row * 132 + chunk * 4];
      }
      __syncthreads();
    }
  }
}

// ------------------------------------------------ phase C body: K/V GEMM + att
__device__ __forceinline__ void kv_att_body(int nblk, int hg, int b, int tid,
                                            const u16* A, const u16* Bt,
                                            float* att4, u16* smem) {
  const int wave = tid >> 6, lane = tid & 63;
  const int n0 = nblk * 128;
  const u16* Bb = Bt + (size_t)b * (size_t)NSP * CCH;

  const int lrow = lane >> 3;                   // 0..7
  const int kcl  = ((lane & 7) ^ lrow) * 8;     // swizzled k element offset
  const u16* pA[4]; const u16* pB[4];
#pragma unroll
  for (int j = 0; j < 4; ++j) {
    // local row j*32+wave*8+lrow: [0,64)=K rows, [64,128)=V rows of head pair hg
    const int arow = 256 + (j >> 1) * 256 + hg * 64 + (j & 1) * 32 + wave * 8 + lrow;
    pA[j] = A  + (size_t)arow * CCH + kcl;
    pB[j] = Bb + (size_t)(n0 + j * 32 + wave * 8 + lrow) * CCH + kcl;
  }
  u16* lA = smem;                               // 16 KB
  u16* lB = smem + 8192;                        // 16 KB

  const int wm = wave >> 1, wn = wave & 1;
  f32x4 acc[4][4];
#pragma unroll
  for (int i = 0; i < 4; ++i)
#pragma unroll
    for (int j = 0; j < 4; ++j) acc[i][j] = (f32x4){0.f, 0.f, 0.f, 0.f};

  for (int it = 0; it < 4; ++it) {              // K = 256, BK = 64
#pragma unroll
    for (int j = 0; j < 4; ++j) {
      __builtin_amdgcn_global_load_lds(GLB(pA[j]), LDSP(lA + (j * 256 + wave * 64) * 8), 16, 0, 0);
      __builtin_amdgcn_global_load_lds(GLB(pB[j]), LDSP(lB + (j * 256 + wave * 64) * 8), 16, 0, 0);
      pA[j] += 64; pB[j] += 64;
    }
    __syncthreads();
#pragma unroll
    for (int w = 0; w < 2; ++w) {
      const int kcf = w * 4 + (lane >> 4);
      short8 af[4], bfr[4];
#pragma unroll
      for (int mt = 0; mt < 4; ++mt) {
        const int row = wm * 64 + mt * 16 + (lane & 15);
        af[mt] = *(const short8*)&lA[(row * 8 + (kcf ^ (row & 7))) * 8];
      }
#pragma unroll
      for (int nt = 0; nt < 4; ++nt) {
        const int row = wn * 64 + nt * 16 + (lane & 15);
        bfr[nt] = *(const short8*)&lB[(row * 8 + (kcf ^ (row & 7))) * 8];
      }
#pragma unroll
      for (int mt = 0; mt < 4; ++mt)
#pragma unroll
        for (int nt = 0; nt < 4; ++nt)
          acc[mt][nt] = __builtin_amdgcn_mfma_f32_16x16x32_bf16(af[mt], bfr[nt], acc[mt][nt], 0, 0, 0);
    }
    __syncthreads();
  }

  // epilogue -> clK (exp'ed K rows) / clV, [64][136] each
  u16* clK = smem;                              // bytes [0, 17408)
  u16* clV = smem + 8704;                       // bytes [17408, 34816)
  {
    const int rbase = (lane >> 4) * 4;
    if (wm == 0) {                              // rows 0..63 = K
#pragma unroll
      for (int mt = 0; mt < 4; ++mt)
#pragma unroll
        for (int nt = 0; nt < 4; ++nt)
#pragma unroll
          for (int r = 0; r < 4; ++r) {
            const int row = mt * 16 + rbase + r;
            const int col = wn * 64 + nt * 16 + (lane & 15);
            clK[row * 136 + col] = f2bf(__expf(acc[mt][nt][r]));
          }
    } else {                                    // rows 64..127 = V
#pragma unroll
      for (int mt = 0; mt < 4; ++mt)
#pragma unroll
        for (int nt = 0; nt < 4; ++nt)
#pragma unroll
          for (int r = 0; r < 4; ++r) {
            const int row = mt * 16 + rbase + r;
            const int col = wn * 64 + nt * 16 + (lane & 15);
            clV[row * 136 + col] = f2bf(acc[mt][nt][r]);
          }
    }
  }
  __syncthreads();                              // clK + clV visible to all waves

  // att phase: wave = (head hh in pair, n-half)
  const int hh = wave >> 1, nhalf = wave & 1;
  const int bh = b * 8 + hg * 2 + hh;
  f32x4 a2[2][2], al[2];
#pragma unroll
  for (int i = 0; i < 2; ++i) {
    al[i] = (f32x4){0.f, 0.f, 0.f, 0.f};
#pragma unroll
    for (int j = 0; j < 2; ++j) a2[i][j] = (f32x4){0.f, 0.f, 0.f, 0.f};
  }
  short8 ones;
#pragma unroll
  for (int j = 0; j < 8; ++j) ones[j] = (short)0x3F80;   // bf16 1.0

  const int rr = lane & 15, cc8 = (lane >> 4) * 8;
#pragma unroll
  for (int c = 0; c < 2; ++c) {                 // 2 chunks of 32 n per wave
    const int n = (nhalf * 2 + c) * 32 + cc8;
    short8 ek0 = *(const short8*)&clK[(hh * 32 + rr) * 136 + n];
    short8 ek1 = *(const short8*)&clK[(hh * 32 + 16 + rr) * 136 + n];
    short8 v0  = *(const short8*)&clV[(hh * 32 + rr) * 136 + n];
    short8 v1  = *(const short8*)&clV[(hh * 32 + 16 + rr) * 136 + n];
    a2[0][0] = __builtin_amdgcn_mfma_f32_16x16x32_bf16(ek0, v0, a2[0][0], 0, 0, 0);
    a2[0][1] = __builtin_amdgcn_mfma_f32_16x16x32_bf16(ek0, v1, a2[0][1], 0, 0, 0);
    a2[1][0] = __builtin_amdgcn_mfma_f32_16x16x32_bf16(ek1, v0, a2[1][0], 0, 0, 0);
    a2[1][1] = __builtin_amdgcn_mfma_f32_16x16x32_bf16(ek1, v1, a2[1][1], 0, 0, 0);
    al[0]    = __builtin_amdgcn_mfma_f32_16x16x32_bf16(ek0, ones, al[0], 0, 0, 0);
    al[1]    = __builtin_amdgcn_mfma_f32_16x16x32_bf16(ek1, ones, al[1], 0, 0, 0);
  }
  __syncthreads();                              // done reading clK/clV

  // pair-reduce the two n-half waves of each head in LDS, then atomicAdd
  float* red  = (float*)smem;                   // [2][32][34] f32 (8704 B)
  float* redl = red + 2176;                     // [2][32]
  const int dq = (lane >> 4) * 4;
  if (nhalf == 1) {
#pragma unroll
    for (int dh = 0; dh < 2; ++dh) {
#pragma unroll
      for (int eh = 0; eh < 2; ++eh)
#pragma unroll
        for (int j = 0; j < 4; ++j)
          red[hh * 1088 + (dh * 16 + dq + j) * 34 + eh * 16 + rr] = a2[dh][eh][j];
      if (rr == 0)
#pragma unroll
        for (int j = 0; j < 4; ++j) redl[hh * 32 + dh * 16 + dq + j] = al[dh][j];
    }
  }
  __syncthreads();
  if (nhalf == 0) {
    float* ap = att4 + (size_t)bh * 1056;
#pragma unroll
    for (int dh = 0; dh < 2; ++dh) {
#pragma unroll
      for (int eh = 0; eh < 2; ++eh)
#pragma unroll
        for (int j = 0; j < 4; ++j) {
          const int d = dh * 16 + dq + j, e = eh * 16 + rr;
          atomicAdd(&ap[d * 32 + e], a2[dh][eh][j] + red[hh * 1088 + d * 34 + e]);
        }
      if (rr == 0)
#pragma unroll
        for (int j = 0; j < 4; ++j) {
          const int d = dh * 16 + dq + j;
          atomicAdd(&ap[1024 + d], al[dh][j] + redl[hh * 32 + d]);
        }
    }
  }
}

// ------------------------------------------------ phase D1 body: W2 = wp @ blockdiag(att/l)
__device__ __forceinline__ void w2_body(int blk, int tid, const u16* wp_bf,
                                        const float* att4, u16* W2) {
  const int b = blk >> 4;
  const int o0 = (blk & 15) * 16;
  const int h = tid >> 5, d = tid & 31;
  const float* ap = att4 + ((size_t)b * 8 + h) * 1056;
  const float linv = 1.f / ap[1024 + d];
  float as[32];
#pragma unroll
  for (int e = 0; e < 32; ++e) as[e] = ap[d * 32 + e] * linv;
  u16* w2p = W2 + (size_t)b * 65536;
  for (int oi = 0; oi < 16; ++oi) {
    const int o = o0 + oi;
    const uint4* wr = (const uint4*)(wp_bf + o * 256 + h * 32);
    float acc = 0.f;
#pragma unroll
    for (int j = 0; j < 4; ++j) {
      uint4 u = wr[j];
      const u16* w8 = (const u16*)&u;
#pragma unroll
      for (int t = 0; t < 8; ++t) acc += bf2f(w8[t]) * as[j * 8 + t];
    }
    w2p[o * 256 + tid] = f2bf(acc);             // coalesced u16 row writes
  }
}

// ================================================ fallback path (R5 verbatim)
__global__ __launch_bounds__(256) void prep_kernel(const float* __restrict__ x,
                                                   const float* __restrict__ wq,
                                                   const float* __restrict__ wp,
                                                   float2* __restrict__ stats,
                                                   float* __restrict__ att4,
                                                   u16* __restrict__ wbf,
                                                   u16* __restrict__ wqT) {
  __shared__ __align__(16) u16 smem[17408];
  prep_body(blockIdx.x, threadIdx.x, x, wq, wp, stats, att4, wbf, wqT, smem);
}

__global__ __launch_bounds__(256) void gn_apply_t(const float* __restrict__ x,
                                                  const float* __restrict__ gw,
                                                  const float* __restrict__ gb,
                                                  const float2* __restrict__ stats,
                                                  u16* __restrict__ xnT) {
  __shared__ __align__(16) u16 smem[17408];
  gn_apply_body(blockIdx.x, blockIdx.y, blockIdx.z, threadIdx.x, x, gw, gb, stats, xnT, smem);
}

template <int OUTF32>
__global__ __launch_bounds__(256) void gemm_mfma(const u16* __restrict__ A,
                                                 const u16* __restrict__ Bt,
                                                 const float* __restrict__ bias,
                                                 void* __restrict__ Cm, int M,
                                                 int aBatch, long btStride, int ldc) {
  __shared__ __align__(16) u16 smem[17408];
  gemm_body<OUTF32>(A, Bt, bias, Cm, M, aBatch, btStride, ldc,
                    blockIdx.x * 128, blockIdx.y * 128, blockIdx.z,
                    threadIdx.x, smem);
}

__global__ __launch_bounds__(256, 4) void gemm_kv_att(const u16* __restrict__ A,
                                                      const u16* __restrict__ Bt,
                                                      float* __restrict__ att4) {
  __shared__ __align__(16) u16 smem[17408];
  kv_att_body(blockIdx.x, blockIdx.y, blockIdx.z, threadIdx.x, A, Bt, att4, smem);
}

__global__ __launch_bounds__(256) void w2_kernel(const u16* __restrict__ wp_bf,
                                                 const float* __restrict__ att4,
                                                 u16* __restrict__ W2) {
  w2_body(blockIdx.x, threadIdx.x, wp_bf, att4, W2);
}

// ================================================ cooperative path
__global__ __launch_bounds__(256, 4) void fused_all(
    const float* __restrict__ x, const float* __restrict__ gn_w,
    const float* __restrict__ gn_b, const float* __restrict__ w_qkv,
    const float* __restrict__ w_proj, const float* __restrict__ b_proj,
    float* __restrict__ out, u16* __restrict__ xnT, u16* __restrict__ wbf,
    u16* __restrict__ wqT, u16* __restrict__ W2, u16* __restrict__ W3,
    float* __restrict__ att4, float2* __restrict__ stats) {
  __shared__ __align__(16) u16 smem[17408];     // 34816 B
  cg::grid_group grid = cg::this_grid();
  const int bid = blockIdx.x, tid = threadIdx.x;
  const int g = gridDim.x;
  const u16* wq_bf = wbf;
  const u16* wp_bf = wbf + 196608;

  // A: prep (784 items)
  for (int i = bid; i < 784; i += g) {
    prep_body(i, tid, x, w_qkv, w_proj, stats, att4, wbf, wqT, smem);
    __syncthreads();
  }
  __threadfence();
  grid.sync();

  // B: GN apply+transpose (4096 items = (64,4,16))
  for (int it = bid; it < 4096; it += g) {
    gn_apply_body(it & 63, (it >> 6) & 3, it >> 8, tid, x, gn_w, gn_b, stats, xnT, smem);
    __syncthreads();
  }
  __threadfence();
  grid.sync();

  // C: fused K/V gemm + att (2048 items = (32,4,16))
  for (int it = bid; it < 2048; it += g) {
    kv_att_body(it & 31, (it >> 5) & 3, it >> 7, tid, wq_bf, xnT, att4, smem);
    __syncthreads();
  }
  __threadfence();
  grid.sync();

  // D1: W2 (256 items)
  for (int i = bid; i < 256; i += g) w2_body(i, tid, wp_bf, att4, W2);
  __threadfence();
  grid.sync();

  // D2: W3_b = W2_b @ Wq_q  (64 items = (2,2,16), ldc=256)
  for (int i = bid; i < 64; i += g) {
    gemm_body<0>(W2, wqT, nullptr, W3, CCH, 65536, 0L, CCH,
                 (i & 1) * 128, ((i >> 1) & 1) * 128, i >> 2, tid, smem);
    __syncthreads();
  }
  __threadfence();
  grid.sync();

  // E: out = W3_b @ xn + b_proj  (1024 items = (32,2,16), ldc=NSP)
  for (int it = bid; it < 1024; it += g) {
    gemm_body<1>(W3, xnT, b_proj, out, CCH, 65536, (long)NSP * CCH, NSP,
                 (it & 31) * 128, ((it >> 5) & 1) * 128, it >> 6, tid, smem);
    __syncthreads();
  }
}

// ------------------------------------------------ launch
extern "C" void kernel_launch(void* const* d_in, const int* in_sizes, int n_in,
                              void* d_out, int out_size, void* d_ws, size_t ws_size,
                              hipStream_t stream) {
  const float* x      = (const float*)d_in[0];
  const float* gn_w   = (const float*)d_in[1];
  const float* gn_b   = (const float*)d_in[2];
  const float* w_qkv  = (const float*)d_in[3];
  const float* w_proj = (const float*)d_in[4];
  const float* b_proj = (const float*)d_in[5];
  float* out = (float*)d_out;

  char* ws = (char*)d_ws;
  u16*    xnT   = (u16*)ws;                                 // 32 MiB [b][n][c]
  u16*    wbf   = (u16*)(ws + 33554432ull);                 // 512 KiB (wq + wp bf16)
  u16*    wqT   = (u16*)(ws + 34078720ull);                 // 128 KiB (Wq_q^T [c][d])
  u16*    W2    = (u16*)(ws + 34209792ull);                 // 2 MiB [b][256][256]
  u16*    W3    = (u16*)(ws + 36306944ull);                 // 2 MiB [b][256][256]
  float*  att4  = (float*)(ws + 38404096ull);               // 540672 B
  float2* stats = (float2*)(ws + 38944768ull);              // 4 KiB
  u16* wq_bf = wbf;
  u16* wp_bf = wbf + 196608;

  // gate: cooperative path only if the RUNTIME guarantees 1024 co-resident
  // blocks (R6 post-mortem: unvalidated coop launch was rejected -> zeros).
  static int coop_state = 0;                    // 0 undecided, 1 coop, -1 fallback
  if (coop_state == 0) {
    int occ = 0;
    hipError_t e = hipOccupancyMaxActiveBlocksPerMultiprocessor(
        &occ, (const void*)fused_all, 256, 0);
    coop_state = (e == hipSuccess && occ >= 4) ? 1 : -1;
  }
  if (coop_state == 1) {
    void* args[14] = {
      (void*)&x, (void*)&gn_w, (void*)&gn_b, (void*)&w_qkv, (void*)&w_proj,
      (void*)&b_proj, (void*)&out, (void*)&xnT, (void*)&wbf, (void*)&wqT,
      (void*)&W2, (void*)&W3, (void*)&att4, (void*)&stats
    };
    hipError_t e = hipLaunchCooperativeKernel((void*)fused_all, dim3(1024),
                                              dim3(256), args, 0, stream);
    if (e == hipSuccess) return;
    coop_state = -1;                            // fall through to safe path
  }

  // fallback: proven R5 pipeline (208 us)
  prep_kernel<<<784, 256, 0, stream>>>(x, w_qkv, w_proj, stats, att4, wbf, wqT);
  gn_apply_t<<<dim3(64, 4, 16), 256, 0, stream>>>(x, gn_w, gn_b, stats, xnT);
  gemm_kv_att<<<dim3(32, 4, 16), 256, 0, stream>>>(wq_bf, xnT, att4);
  w2_kernel<<<256, 256, 0, stream>>>(wp_bf, att4, W2);
  gemm_mfma<0><<<dim3(2, 2, 16), 256, 0, stream>>>(W2, wqT, nullptr, W3,
                                                   CCH, 65536, 0L, CCH);
  gemm_mfma<1><<<dim3(32, 2, 16), 256, 0, stream>>>(W3, xnT, b_proj, out,
                                                    CCH, 65536, (long)NSP * CCH, NSP);
}